// Round 9
// baseline (370.953 us; speedup 1.0000x reference)
//
#include <hip/hip_runtime.h>
#include <hip/hip_bf16.h>

#define Bc 16
#define Nn 4096
#define Cc 128
#define Ee 12288
#define Mm 64
#define NEG_SLOPE 0.2f
#define MARGIN 4.2f
#define NCH 32  // K-split chunks for es/oute GEMMs (4096/32 = 128 n per chunk) -> 1024 blocks

typedef __attribute__((ext_vector_type(8))) short bfrag;   // 8 bf16 = 4 VGPR
typedef __attribute__((ext_vector_type(4))) float f32x4;   // MFMA accumulator

__device__ inline unsigned short f2bf_rne(float f) {
    unsigned u = __float_as_uint(f);
    unsigned r = u + 0x7FFFu + ((u >> 16) & 1u);
    return (unsigned short)(r >> 16);
}
__device__ inline float bfbits2f(unsigned short h) {
    return __uint_as_float(((unsigned)h) << 16);
}
// split f32 -> bf16 hi (trunc) + bf16 lo (rne of residual)
__device__ inline void split1(float f, unsigned short& h, unsigned short& lo) {
    unsigned u = __float_as_uint(f);
    unsigned hb = u & 0xFFFF0000u;
    float r = f - __uint_as_float(hb);
    unsigned ru = __float_as_uint(r);
    ru += 0x7FFFu + ((ru >> 16) & 1u);
    h = (unsigned short)(u >> 16);
    lo = (unsigned short)(ru >> 16);
}
__device__ inline void split8(const float* f, bfrag& h, bfrag& l) {
#pragma unroll
    for (int j = 0; j < 8; ++j) {
        unsigned short hh, ll;
        split1(f[j], hh, ll);
        h[j] = (short)hh; l[j] = (short)ll;
    }
}

// ---------------- prep: wsplit (blocks 0-63) + hist/Acnt (blocks 64-111) -------------
__global__ __launch_bounds__(256) void prep_kernel(const float* __restrict__ w,
                                                   const int* __restrict__ nodes,
                                                   const int* __restrict__ edges,
                                                   unsigned short* __restrict__ wsplit,
                                                   int* __restrict__ deg_n,
                                                   int* __restrict__ deg_m,
                                                   float* __restrict__ Acnt) {
    int blk = blockIdx.x, t = threadIdx.x;
    if (blk < 64) {
        int idx = blk * 256 + t;  // 16384 = 128*128
        int k = idx >> 7, c = idx & 127;
        float v = w[k * 128 + c];
        unsigned short h, lo;
        split1(v, h, lo);
        int byteoff = c * 256 + ((2 * k) ^ ((c & 7) << 4));
        *(unsigned short*)((char*)wsplit + byteoff) = h;
        *(unsigned short*)((char*)wsplit + 32768 + byteoff) = lo;
    } else {
        int e = (blk - 64) * 256 + t;  // 12288 = 48*256
        int n = nodes[e], m = edges[e];
        atomicAdd(&deg_n[n], 1);
        atomicAdd(&deg_m[m], 1);
        atomicAdd(&Acnt[m * 4096 + n], 1.0f);
    }
}

// ---------------- GEMM via bf16 split MFMA: xwT = (x @ w)^T as bf16 hi/lo -------------
__global__ __launch_bounds__(256) void gemm_xw(const float* __restrict__ x,
                                               const unsigned short* __restrict__ wsplit,
                                               const float* __restrict__ att,
                                               unsigned short* __restrict__ xwTh,
                                               unsigned short* __restrict__ xwTl,
                                               float* __restrict__ p,
                                               float* __restrict__ S1) {
    __shared__ unsigned short wlds[32768];  // 64KB: whT_swz | wlT_swz
    int t = threadIdx.x;
    {
        const float4* g4 = (const float4*)wsplit;
        float4* l4 = (float4*)wlds;
#pragma unroll
        for (int i = 0; i < 16; ++i) l4[i * 256 + t] = g4[i * 256 + t];
    }
    __syncthreads();

    int w = t >> 6, l = t & 63;
    int lrow = l & 15, lk = l >> 4;
    int rowbase = blockIdx.x * 128 + w * 32;

    f32x4 acc[2][8];
#pragma unroll
    for (int ti = 0; ti < 2; ++ti)
#pragma unroll
        for (int tj = 0; tj < 8; ++tj) acc[ti][tj] = (f32x4){0.f, 0.f, 0.f, 0.f};

    for (int ks = 0; ks < 4; ++ks) {
        bfrag bh[8], bl[8];
        int kbyte = (64 * ks + 16 * lk) ^ ((l & 7) << 4);
#pragma unroll
        for (int tj = 0; tj < 8; ++tj) {
            const char* base = (const char*)wlds + (tj * 16 + lrow) * 256 + kbyte;
            bh[tj] = *(const bfrag*)base;
            bl[tj] = *(const bfrag*)(base + 32768);
        }
#pragma unroll
        for (int ti = 0; ti < 2; ++ti) {
            int row = rowbase + ti * 16 + lrow;
            const float4* xp = (const float4*)(x + (size_t)row * 128 + ks * 32 + lk * 8);
            float4 v0 = xp[0], v1 = xp[1];
            float fa[8] = {v0.x, v0.y, v0.z, v0.w, v1.x, v1.y, v1.z, v1.w};
            bfrag ah, al;
#pragma unroll
            for (int j = 0; j < 8; ++j) {
                unsigned short hh, ll;
                split1(fa[j], hh, ll);
                ah[j] = (short)hh; al[j] = (short)ll;
            }
#pragma unroll
            for (int tj = 0; tj < 8; ++tj) {
                acc[ti][tj] = __builtin_amdgcn_mfma_f32_16x16x32_bf16(ah, bh[tj], acc[ti][tj], 0, 0, 0);
                acc[ti][tj] = __builtin_amdgcn_mfma_f32_16x16x32_bf16(ah, bl[tj], acc[ti][tj], 0, 0, 0);
                acc[ti][tj] = __builtin_amdgcn_mfma_f32_16x16x32_bf16(al, bh[tj], acc[ti][tj], 0, 0, 0);
            }
        }
    }

    // epilogue A: xwT packed bf16 hi/lo writes
#pragma unroll
    for (int ti = 0; ti < 2; ++ti) {
#pragma unroll
        for (int tj = 0; tj < 8; ++tj) {
            int rr0 = rowbase + ti * 16 + lk * 4;
            int b = rr0 >> 12, n0 = rr0 & 4095;
            int slot = b * 128 + tj * 16 + lrow;
            ushort4 hv, lv;
            split1(acc[ti][tj][0], hv.x, lv.x);
            split1(acc[ti][tj][1], hv.y, lv.y);
            split1(acc[ti][tj][2], hv.z, lv.z);
            split1(acc[ti][tj][3], hv.w, lv.w);
            *(ushort4*)(xwTh + (size_t)slot * 4096 + n0) = hv;
            *(ushort4*)(xwTl + (size_t)slot * 4096 + n0) = lv;
        }
    }
    // epilogue B: p / S1 (full f32 precision)
    float aw_[8];
#pragma unroll
    for (int tj = 0; tj < 8; ++tj) aw_[tj] = att[tj * 16 + lrow];
#pragma unroll
    for (int ti = 0; ti < 2; ++ti) {
#pragma unroll
        for (int v = 0; v < 4; ++v) {
            int rr = rowbase + ti * 16 + lk * 4 + v;
            int b = rr >> 12, n = rr & 4095;
            float pd = 0.f, ss = 0.f;
#pragma unroll
            for (int tj = 0; tj < 8; ++tj) {
                float val = acc[ti][tj][v];
                pd += val * aw_[tj];
                ss += val;
            }
#pragma unroll
            for (int m = 1; m < 16; m <<= 1) {
                pd += __shfl_xor(pd, m, 64);
                ss += __shfl_xor(ss, m, 64);
            }
            if (lrow == 0) {
                p[n * 16 + b] = pd;
                atomicAdd(&S1[n], ss);
            }
        }
    }
}

// ---------------- exclusive scan (node side only) ----------------
__global__ __launch_bounds__(1024) void scan_kernel(const int* __restrict__ deg_n,
                                                    int* __restrict__ off_n,
                                                    int* __restrict__ cur_n) {
    __shared__ int s[1024];
    int t = threadIdx.x;
    int base = t * 4;
    int d0 = deg_n[base], d1 = deg_n[base + 1], d2 = deg_n[base + 2], d3 = deg_n[base + 3];
    int local = d0 + d1 + d2 + d3;
    s[t] = local;
    __syncthreads();
    for (int offs = 1; offs < 1024; offs <<= 1) {
        int v = (t >= offs) ? s[t - offs] : 0;
        __syncthreads();
        s[t] += v;
        __syncthreads();
    }
    int excl = s[t] - local;
    int o0 = excl, o1 = excl + d0, o2 = excl + d0 + d1, o3 = excl + d0 + d1 + d2;
    off_n[base] = o0; off_n[base + 1] = o1; off_n[base + 2] = o2; off_n[base + 3] = o3;
    cur_n[base] = o0; cur_n[base + 1] = o1; cur_n[base + 2] = o2; cur_n[base + 3] = o3;
    if (t == 1023) off_n[4096] = s[1023];
}

// ---------------- fill node-CSR: gedge_n[pos] = hyperedge id ----------------
__global__ void fill_kernel(const int* __restrict__ nodes, const int* __restrict__ edges,
                            int* __restrict__ cur_n, int* __restrict__ gedge_n) {
    int e = blockIdx.x * 256 + threadIdx.x;
    if (e < Ee) {
        int pos = atomicAdd(&cur_n[nodes[e]], 1);
        gedge_n[pos] = edges[e];
    }
}

// ---------------- es GEMM (K-split): es[m][slot] += sum_{n in chunk} Acnt*xwT ---------
// grid (32 slot-blocks, NCH k-chunks) = 1024 blocks; es/q/T atomically accumulated.
__global__ __launch_bounds__(256) void es_gemm(const float* __restrict__ Acnt,
                                               const unsigned short* __restrict__ xwTh,
                                               const unsigned short* __restrict__ xwTl,
                                               const float* __restrict__ att,
                                               float* __restrict__ es,
                                               float* __restrict__ q,
                                               float* __restrict__ T) {
    int t = threadIdx.x, w = t >> 6, l = t & 63;
    int lrow = l & 15, lk = l >> 4;
    int slot0 = blockIdx.x * 64;
    int kbase = blockIdx.y * (4096 / NCH);
    f32x4 acc[4];
#pragma unroll
    for (int tj = 0; tj < 4; ++tj) acc[tj] = (f32x4){0.f, 0.f, 0.f, 0.f};
    const float* arow = Acnt + (size_t)(w * 16 + lrow) * 4096;
#pragma unroll
    for (int ks = 0; ks < 4096 / NCH / 32; ++ks) {
        int n0 = kbase + ks * 32 + lk * 8;
        const float* ap = arow + n0;
        bfrag af;
#pragma unroll
        for (int j = 0; j < 8; ++j) af[j] = (short)(__float_as_uint(ap[j]) >> 16);  // counts exact
#pragma unroll
        for (int tj = 0; tj < 4; ++tj) {
            size_t off = (size_t)(slot0 + tj * 16 + lrow) * 4096 + n0;
            bfrag bh = *(const bfrag*)(xwTh + off);
            bfrag bl = *(const bfrag*)(xwTl + off);
            acc[tj] = __builtin_amdgcn_mfma_f32_16x16x32_bf16(af, bh, acc[tj], 0, 0, 0);
            acc[tj] = __builtin_amdgcn_mfma_f32_16x16x32_bf16(af, bl, acc[tj], 0, 0, 0);
        }
    }
    int b = slot0 >> 7;
    float qp[4] = {0, 0, 0, 0}, tp[4] = {0, 0, 0, 0};
#pragma unroll
    for (int tj = 0; tj < 4; ++tj) {
        int slot = slot0 + tj * 16 + lrow;
        float a2 = att[128 + (slot & 127)];
#pragma unroll
        for (int reg = 0; reg < 4; ++reg) {
            int mm = w * 16 + lk * 4 + reg;
            float val = acc[tj][reg];
            atomicAdd(&es[mm * 2048 + slot], val);
            qp[reg] += val * a2;
            tp[reg] += val;
        }
    }
#pragma unroll
    for (int msk = 1; msk < 16; msk <<= 1) {
#pragma unroll
        for (int reg = 0; reg < 4; ++reg) {
            qp[reg] += __shfl_xor(qp[reg], msk, 64);
            tp[reg] += __shfl_xor(tp[reg], msk, 64);
        }
    }
    if (lrow == 0) {
#pragma unroll
        for (int reg = 0; reg < 4; ++reg) {
            int mm = w * 16 + lk * 4 + reg;
            atomicAdd(&q[mm * 16 + b], qp[reg]);
            atomicAdd(&T[mm], tp[reg]);
        }
    }
}

// ---------------- pairwise hyperedge loss (norms inline) ----------------
__global__ __launch_bounds__(256) void loss_kernel(const float* __restrict__ es,
                                                   float* __restrict__ loss_part) {
    int m = blockIdx.x, t = threadIdx.x;
    __shared__ float esm[2048];
    __shared__ float sml[16];
    for (int i = t; i < 2048; i += 256) esm[i] = es[m * 2048 + i];
    __syncthreads();
    if (t < 16) {
        float s = 0.f;
        const float* r = esm + t * 128;
        for (int c = 0; c < 128; ++c) s += r[c] * r[c];
        sml[t] = s;
    }
    __syncthreads();
    int n = t >> 2, bq = t & 3;
    float part = 0.f;
#pragma unroll
    for (int u = 0; u < 4; u++) {
        int b = bq * 4 + u;
        float inner = 0.f, sn = 0.f;
        const float* er = es + n * 2048 + b * 128;
        const float* em = esm + b * 128;
        for (int c = 0; c < 128; c += 4) {
            float4 a = *(const float4*)(em + c);
            float4 o = *(const float4*)(er + c);
            inner += a.x * o.x + a.y * o.y + a.z * o.z + a.w * o.w;
            sn += o.x * o.x + o.y * o.y + o.z * o.z + o.w * o.w;
        }
        float sm = sml[b];
        float cosv = inner / (sqrtf(sm) * sqrtf(sn));
        float d2 = sm + sn - 2.f * inner;
        float dist = sqrtf(fmaxf(d2, 0.f));
        part += cosv * dist + (1.f - cosv) * fmaxf(MARGIN - dist, 0.f);
    }
    part += __shfl_xor(part, 1, 64);
    part += __shfl_xor(part, 2, 64);
    float labs = fabsf(part * (1.f / 16.f));
    __shared__ float pl[64];
    if (bq == 0) pl[n] = labs;
    __syncthreads();
    if (t < 64) {
        float v = pl[t];
        for (int k = 1; k < 64; k <<= 1) v += __shfl_xor(v, k, 64);
        if (t == 0) loss_part[m] = v;
    }
}

// ---------------- alpha softmax + Wa/Wb scatter ----------------
__global__ __launch_bounds__(256) void alpha_wab(const int* __restrict__ off_n,
                                                 const int* __restrict__ gedge_n,
                                                 const float* __restrict__ p,
                                                 const float* __restrict__ q,
                                                 const int* __restrict__ deg_m,
                                                 float* __restrict__ Wa,
                                                 float* __restrict__ Wb) {
    int idx = blockIdx.x * 256 + threadIdx.x;  // 65536 = N*B
    int b = idx & 15, n = idx >> 4;
    int beg = off_n[n], end = off_n[n + 1];
    if (beg == end) return;
    float pb = p[n * 16 + b];
    float lf = pb + q[gedge_n[beg] * 16 + b];
    lf = lf >= 0.f ? lf : NEG_SLOPE * lf;
    float ssum = 0.f;
    for (int i = beg; i < end; i++) {
        float lg = pb + q[gedge_n[i] * 16 + b];
        lg = lg >= 0.f ? lg : NEG_SLOPE * lg;
        ssum += __expf(lg - lf);
    }
    float inv = 1.f / ssum;
    for (int i = beg; i < end; i++) {
        int m = gedge_n[i];
        float lg = pb + q[m * 16 + b];
        lg = lg >= 0.f ? lg : NEG_SLOPE * lg;
        float a = __expf(lg - lf) * inv;
        float bninv = 1.f / (float)deg_m[m];
        atomicAdd(&Wa[((size_t)b * 64 + m) * 4096 + n], a);
        atomicAdd(&Wb[((size_t)b * 4096 + n) * 64 + m], a * bninv);
    }
}

// ---------------- ouT GEMM (K-split): ouT[slot][m] += sum_n xwT[slot][n]*Wa[b][m][n] --
__global__ __launch_bounds__(256) void oute_gemm(const unsigned short* __restrict__ xwTh,
                                                 const unsigned short* __restrict__ xwTl,
                                                 const float* __restrict__ Wa,
                                                 float* __restrict__ ouT) {
    int t = threadIdx.x, w = t >> 6, l = t & 63;
    int lrow = l & 15, lk = l >> 4;
    int slot0 = blockIdx.x * 64;
    int b = slot0 >> 7;
    int kbase = blockIdx.y * (4096 / NCH);
    f32x4 acc[4];
#pragma unroll
    for (int tj = 0; tj < 4; ++tj) acc[tj] = (f32x4){0.f, 0.f, 0.f, 0.f};
    int srow = slot0 + w * 16 + lrow;
    const unsigned short* xh = xwTh + (size_t)srow * 4096;
    const unsigned short* xl = xwTl + (size_t)srow * 4096;
    const float* wab = Wa + (size_t)b * 64 * 4096;
#pragma unroll
    for (int ks = 0; ks < 4096 / NCH / 32; ++ks) {
        int n0 = kbase + ks * 32 + lk * 8;
        bfrag ah = *(const bfrag*)(xh + n0);
        bfrag al = *(const bfrag*)(xl + n0);
#pragma unroll
        for (int tj = 0; tj < 4; ++tj) {
            int mcol = tj * 16 + lrow;
            bfrag wh, wl_;
            split8(wab + (size_t)mcol * 4096 + n0, wh, wl_);
            acc[tj] = __builtin_amdgcn_mfma_f32_16x16x32_bf16(ah, wh, acc[tj], 0, 0, 0);
            acc[tj] = __builtin_amdgcn_mfma_f32_16x16x32_bf16(ah, wl_, acc[tj], 0, 0, 0);
            acc[tj] = __builtin_amdgcn_mfma_f32_16x16x32_bf16(al, wh, acc[tj], 0, 0, 0);
        }
    }
#pragma unroll
    for (int tj = 0; tj < 4; ++tj) {
        int mcol = tj * 16 + lrow;
#pragma unroll
        for (int reg = 0; reg < 4; ++reg) {
            int slot = slot0 + w * 16 + lk * 4 + reg;
            atomicAdd(&ouT[slot * 64 + mcol], acc[tj][reg]);
        }
    }
}

// ---------------- out GEMM: out[b][n][c] = D[n]*sum_m Wb[b][n][m]*ouT[b*128+c][m] -----
// grid (64 n-blocks, 16 b) = 1024 blocks; wave = 16 rows x 128 cols.
__global__ __launch_bounds__(256) void out_gemm(const float* __restrict__ Wb,
                                                const float* __restrict__ ouT,
                                                const int* __restrict__ deg_n,
                                                float* __restrict__ out) {
    int t = threadIdx.x, w = t >> 6, l = t & 63;
    int lrow = l & 15, lk = l >> 4;
    int nbase = blockIdx.x * 64 + w * 16;
    int b = blockIdx.y;
    f32x4 acc[8];
#pragma unroll
    for (int tj = 0; tj < 8; ++tj) acc[tj] = (f32x4){0.f, 0.f, 0.f, 0.f};
#pragma unroll
    for (int ks = 0; ks < 2; ++ks) {
        int m0 = ks * 32 + lk * 8;
        bfrag wh, wl;
        int nr = nbase + lrow;
        split8(Wb + ((size_t)b * 4096 + nr) * 64 + m0, wh, wl);
#pragma unroll
        for (int tj = 0; tj < 8; ++tj) {
            int slot = b * 128 + tj * 16 + lrow;
            bfrag oh, ol;
            split8(ouT + (size_t)slot * 64 + m0, oh, ol);
            acc[tj] = __builtin_amdgcn_mfma_f32_16x16x32_bf16(wh, oh, acc[tj], 0, 0, 0);
            acc[tj] = __builtin_amdgcn_mfma_f32_16x16x32_bf16(wh, ol, acc[tj], 0, 0, 0);
            acc[tj] = __builtin_amdgcn_mfma_f32_16x16x32_bf16(wl, oh, acc[tj], 0, 0, 0);
        }
    }
#pragma unroll
    for (int reg = 0; reg < 4; ++reg) {
        int n = nbase + lk * 4 + reg;
        float d = (float)deg_n[n];
#pragma unroll
        for (int tj = 0; tj < 8; ++tj) {
            out[(size_t)b * 524288 + (size_t)n * 128 + tj * 16 + lrow] = d * acc[tj][reg];
        }
    }
}

// ---------------- finalize scalar ----------------
__global__ __launch_bounds__(256) void finalize_kernel(const int* __restrict__ deg_n,
                                                       const float* __restrict__ S1,
                                                       const int* __restrict__ deg_m,
                                                       const float* __restrict__ T,
                                                       const float* __restrict__ loss_part,
                                                       float* __restrict__ out_scalar) {
    int t = threadIdx.x;
    double a = 0.0;
    for (int n = t; n < 4096; n += 256) a += (double)deg_n[n] * (double)S1[n];
    double bsum = 0.0, lsum = 0.0;
    if (t < 64) {
        bsum = (double)deg_m[t] * (double)T[t];
        lsum = (double)loss_part[t];
    }
    __shared__ double sa[256], sb[256], sl[256];
    sa[t] = a; sb[t] = bsum; sl[t] = lsum;
    __syncthreads();
    for (int s = 128; s > 0; s >>= 1) {
        if (t < s) { sa[t] += sa[t + s]; sb[t] += sb[t + s]; sl[t] += sl[t + s]; }
        __syncthreads();
    }
    if (t == 0) {
        double mean = (sa[0] - sb[0]) / 25165824.0;  // E*B*C
        out_scalar[0] = (float)(fabs(mean) + sl[0] / 4225.0);
    }
}

extern "C" void kernel_launch(void* const* d_in, const int* in_sizes, int n_in,
                              void* d_out, int out_size, void* d_ws, size_t ws_size,
                              hipStream_t stream) {
    const float* x = (const float*)d_in[0];
    const int* nodes = (const int*)d_in[1];
    const int* edges = (const int*)d_in[2];
    const float* w = (const float*)d_in[3];
    const float* att = (const float*)d_in[4];
    float* out = (float*)d_out;

    char* ws = (char*)d_ws;
    size_t o = 0;
    unsigned short* xwTh = (unsigned short*)(ws + o); o += (size_t)2048 * 4096 * 2;  // 16 MB
    unsigned short* xwTl = (unsigned short*)(ws + o); o += (size_t)2048 * 4096 * 2;  // 16 MB
    // ---- zero region (one memset): Acnt, Wa, Wb, ouT, es, deg_n, deg_m, S1, q, T ----
    size_t zbase = o;
    float* Acnt = (float*)(ws + o);  o += (size_t)Mm * Nn * 4;            // 1 MB
    float* Wa = (float*)(ws + o);    o += (size_t)Bc * Mm * Nn * 4;       // 16 MB
    float* Wb = (float*)(ws + o);    o += (size_t)Bc * Nn * Mm * 4;       // 16 MB
    float* ouT = (float*)(ws + o);   o += (size_t)2048 * 64 * 4;          // 512 KB
    float* es = (float*)(ws + o);    o += (size_t)Mm * 2048 * 4;          // 512 KB
    int* deg_n = (int*)(ws + o);     o += (size_t)Nn * 4;
    int* deg_m = (int*)(ws + o);     o += (size_t)Mm * 4;
    float* S1 = (float*)(ws + o);    o += (size_t)Nn * 4;
    float* q = (float*)(ws + o);     o += (size_t)Mm * Bc * 4;
    float* T = (float*)(ws + o);     o += (size_t)Mm * 4;
    size_t zlen = o - zbase;
    // ---- end zero region ----
    float* p = (float*)(ws + o);         o += (size_t)Nn * Bc * 4;        // 256 KB
    float* loss_part = (float*)(ws + o); o += (size_t)Mm * 4;
    int* off_n = (int*)(ws + o);         o += (size_t)(Nn + 1) * 4;
    int* cur_n = (int*)(ws + o);         o += (size_t)Nn * 4;
    int* gedge_n = (int*)(ws + o);       o += (size_t)Ee * 4;
    unsigned short* wsplit = (unsigned short*)(ws + o); o += 65536;       // 64 KB

    hipMemsetAsync(ws + zbase, 0, zlen, stream);

    prep_kernel<<<112, 256, 0, stream>>>(w, nodes, edges, wsplit, deg_n, deg_m, Acnt);
    gemm_xw<<<512, 256, 0, stream>>>(x, wsplit, att, xwTh, xwTl, p, S1);
    scan_kernel<<<1, 1024, 0, stream>>>(deg_n, off_n, cur_n);
    fill_kernel<<<48, 256, 0, stream>>>(nodes, edges, cur_n, gedge_n);
    es_gemm<<<dim3(32, NCH), 256, 0, stream>>>(Acnt, xwTh, xwTl, att, es, q, T);
    loss_kernel<<<Mm, 256, 0, stream>>>(es, loss_part);
    alpha_wab<<<256, 256, 0, stream>>>(off_n, gedge_n, p, q, deg_m, Wa, Wb);
    oute_gemm<<<dim3(32, NCH), 256, 0, stream>>>(xwTh, xwTl, Wa, ouT);
    out_gemm<<<dim3(64, 16), 256, 0, stream>>>(Wb, ouT, deg_n, out);
    finalize_kernel<<<1, 256, 0, stream>>>(deg_n, S1, deg_m, T, loss_part, out + (size_t)Bc * Nn * Cc);
}

// Round 10
// 251.894 us; speedup vs baseline: 1.4727x; 1.4727x over previous
//
#include <hip/hip_runtime.h>
#include <hip/hip_bf16.h>

#define Bc 16
#define Nn 4096
#define Cc 128
#define Ee 12288
#define Mm 64
#define NEG_SLOPE 0.2f
#define MARGIN 4.2f
#define NCH 32  // K-split chunks for es/oute GEMMs -> 1024 blocks, partial-buffer reduce

typedef __attribute__((ext_vector_type(8))) short bfrag;   // 8 bf16 = 4 VGPR
typedef __attribute__((ext_vector_type(4))) float f32x4;   // MFMA accumulator

// split f32 -> bf16 hi (trunc) + bf16 lo (rne of residual)
__device__ inline void split1(float f, unsigned short& h, unsigned short& lo) {
    unsigned u = __float_as_uint(f);
    unsigned hb = u & 0xFFFF0000u;
    float r = f - __uint_as_float(hb);
    unsigned ru = __float_as_uint(r);
    ru += 0x7FFFu + ((ru >> 16) & 1u);
    h = (unsigned short)(u >> 16);
    lo = (unsigned short)(ru >> 16);
}
__device__ inline void split8(const float* f, bfrag& h, bfrag& l) {
#pragma unroll
    for (int j = 0; j < 8; ++j) {
        unsigned short hh, ll;
        split1(f[j], hh, ll);
        h[j] = (short)hh; l[j] = (short)ll;
    }
}

// ---------------- prep: wsplit (blocks 0-63) + hist/Acnt/AcntT (blocks 64-111) --------
__global__ __launch_bounds__(256) void prep_kernel(const float* __restrict__ w,
                                                   const int* __restrict__ nodes,
                                                   const int* __restrict__ edges,
                                                   unsigned short* __restrict__ wsplit,
                                                   int* __restrict__ deg_n,
                                                   int* __restrict__ deg_m,
                                                   float* __restrict__ Acnt,
                                                   float* __restrict__ AcntT) {
    int blk = blockIdx.x, t = threadIdx.x;
    if (blk < 64) {
        int idx = blk * 256 + t;  // 16384 = 128*128
        int k = idx >> 7, c = idx & 127;
        float v = w[k * 128 + c];
        unsigned short h, lo;
        split1(v, h, lo);
        int byteoff = c * 256 + ((2 * k) ^ ((c & 7) << 4));
        *(unsigned short*)((char*)wsplit + byteoff) = h;
        *(unsigned short*)((char*)wsplit + 32768 + byteoff) = lo;
    } else {
        int e = (blk - 64) * 256 + t;  // 12288 = 48*256
        int n = nodes[e], m = edges[e];
        atomicAdd(&deg_n[n], 1);
        atomicAdd(&deg_m[m], 1);
        atomicAdd(&Acnt[m * 4096 + n], 1.0f);
        atomicAdd(&AcntT[n * 64 + m], 1.0f);
    }
}

// ---------------- GEMM via bf16 split MFMA: xwT = (x @ w)^T as bf16 hi/lo -------------
__global__ __launch_bounds__(256) void gemm_xw(const float* __restrict__ x,
                                               const unsigned short* __restrict__ wsplit,
                                               const float* __restrict__ att,
                                               unsigned short* __restrict__ xwTh,
                                               unsigned short* __restrict__ xwTl,
                                               float* __restrict__ p,
                                               float* __restrict__ S1) {
    __shared__ unsigned short wlds[32768];  // 64KB: whT_swz | wlT_swz
    int t = threadIdx.x;
    {
        const float4* g4 = (const float4*)wsplit;
        float4* l4 = (float4*)wlds;
#pragma unroll
        for (int i = 0; i < 16; ++i) l4[i * 256 + t] = g4[i * 256 + t];
    }
    __syncthreads();

    int w = t >> 6, l = t & 63;
    int lrow = l & 15, lk = l >> 4;
    int rowbase = blockIdx.x * 128 + w * 32;

    f32x4 acc[2][8];
#pragma unroll
    for (int ti = 0; ti < 2; ++ti)
#pragma unroll
        for (int tj = 0; tj < 8; ++tj) acc[ti][tj] = (f32x4){0.f, 0.f, 0.f, 0.f};

    for (int ks = 0; ks < 4; ++ks) {
        bfrag bh[8], bl[8];
        int kbyte = (64 * ks + 16 * lk) ^ ((l & 7) << 4);
#pragma unroll
        for (int tj = 0; tj < 8; ++tj) {
            const char* base = (const char*)wlds + (tj * 16 + lrow) * 256 + kbyte;
            bh[tj] = *(const bfrag*)base;
            bl[tj] = *(const bfrag*)(base + 32768);
        }
#pragma unroll
        for (int ti = 0; ti < 2; ++ti) {
            int row = rowbase + ti * 16 + lrow;
            const float4* xp = (const float4*)(x + (size_t)row * 128 + ks * 32 + lk * 8);
            float4 v0 = xp[0], v1 = xp[1];
            float fa[8] = {v0.x, v0.y, v0.z, v0.w, v1.x, v1.y, v1.z, v1.w};
            bfrag ah, al;
#pragma unroll
            for (int j = 0; j < 8; ++j) {
                unsigned short hh, ll;
                split1(fa[j], hh, ll);
                ah[j] = (short)hh; al[j] = (short)ll;
            }
#pragma unroll
            for (int tj = 0; tj < 8; ++tj) {
                acc[ti][tj] = __builtin_amdgcn_mfma_f32_16x16x32_bf16(ah, bh[tj], acc[ti][tj], 0, 0, 0);
                acc[ti][tj] = __builtin_amdgcn_mfma_f32_16x16x32_bf16(ah, bl[tj], acc[ti][tj], 0, 0, 0);
                acc[ti][tj] = __builtin_amdgcn_mfma_f32_16x16x32_bf16(al, bh[tj], acc[ti][tj], 0, 0, 0);
            }
        }
    }

    // epilogue A: xwT packed bf16 hi/lo writes
#pragma unroll
    for (int ti = 0; ti < 2; ++ti) {
#pragma unroll
        for (int tj = 0; tj < 8; ++tj) {
            int rr0 = rowbase + ti * 16 + lk * 4;
            int b = rr0 >> 12, n0 = rr0 & 4095;
            int slot = b * 128 + tj * 16 + lrow;
            ushort4 hv, lv;
            split1(acc[ti][tj][0], hv.x, lv.x);
            split1(acc[ti][tj][1], hv.y, lv.y);
            split1(acc[ti][tj][2], hv.z, lv.z);
            split1(acc[ti][tj][3], hv.w, lv.w);
            *(ushort4*)(xwTh + (size_t)slot * 4096 + n0) = hv;
            *(ushort4*)(xwTl + (size_t)slot * 4096 + n0) = lv;
        }
    }
    // epilogue B: p / S1 (full f32 precision)
    float aw_[8];
#pragma unroll
    for (int tj = 0; tj < 8; ++tj) aw_[tj] = att[tj * 16 + lrow];
#pragma unroll
    for (int ti = 0; ti < 2; ++ti) {
#pragma unroll
        for (int v = 0; v < 4; ++v) {
            int rr = rowbase + ti * 16 + lk * 4 + v;
            int b = rr >> 12, n = rr & 4095;
            float pd = 0.f, ss = 0.f;
#pragma unroll
            for (int tj = 0; tj < 8; ++tj) {
                float val = acc[ti][tj][v];
                pd += val * aw_[tj];
                ss += val;
            }
#pragma unroll
            for (int m = 1; m < 16; m <<= 1) {
                pd += __shfl_xor(pd, m, 64);
                ss += __shfl_xor(ss, m, 64);
            }
            if (lrow == 0) {
                p[n * 16 + b] = pd;
                atomicAdd(&S1[n], ss);   // 16K small atomics total, negligible
            }
        }
    }
}

// ---------------- es GEMM (K-split, NO atomics): partial per chunk --------------------
// grid (32 slot-blocks, NCH chunks); es_part[ch][m][slot] plain stores.
__global__ __launch_bounds__(256) void es_gemm(const float* __restrict__ Acnt,
                                               const unsigned short* __restrict__ xwTh,
                                               const unsigned short* __restrict__ xwTl,
                                               float* __restrict__ es_part) {
    int t = threadIdx.x, w = t >> 6, l = t & 63;
    int lrow = l & 15, lk = l >> 4;
    int slot0 = blockIdx.x * 64;
    int kbase = blockIdx.y * (4096 / NCH);
    f32x4 acc[4];
#pragma unroll
    for (int tj = 0; tj < 4; ++tj) acc[tj] = (f32x4){0.f, 0.f, 0.f, 0.f};
    const float* arow = Acnt + (size_t)(w * 16 + lrow) * 4096;
#pragma unroll
    for (int ks = 0; ks < 4096 / NCH / 32; ++ks) {
        int n0 = kbase + ks * 32 + lk * 8;
        const float* ap = arow + n0;
        bfrag af;
#pragma unroll
        for (int j = 0; j < 8; ++j) af[j] = (short)(__float_as_uint(ap[j]) >> 16);  // counts exact
#pragma unroll
        for (int tj = 0; tj < 4; ++tj) {
            size_t off = (size_t)(slot0 + tj * 16 + lrow) * 4096 + n0;
            bfrag bh = *(const bfrag*)(xwTh + off);
            bfrag bl = *(const bfrag*)(xwTl + off);
            acc[tj] = __builtin_amdgcn_mfma_f32_16x16x32_bf16(af, bh, acc[tj], 0, 0, 0);
            acc[tj] = __builtin_amdgcn_mfma_f32_16x16x32_bf16(af, bl, acc[tj], 0, 0, 0);
        }
    }
    float* dst = es_part + (size_t)blockIdx.y * 64 * 2048;
#pragma unroll
    for (int tj = 0; tj < 4; ++tj) {
        int slot = slot0 + tj * 16 + lrow;
#pragma unroll
        for (int reg = 0; reg < 4; ++reg) {
            int mm = w * 16 + lk * 4 + reg;
            dst[mm * 2048 + slot] = acc[tj][reg];
        }
    }
}

// ---------------- es reduce: es = sum_ch es_part; fused q[m][b], T[m] -----------------
__global__ __launch_bounds__(256) void es_reduce(const float* __restrict__ es_part,
                                                 const float* __restrict__ att,
                                                 float* __restrict__ es,
                                                 float* __restrict__ q,
                                                 float* __restrict__ T) {
    int m = blockIdx.x, t = threadIdx.x;
    float v[8] = {0, 0, 0, 0, 0, 0, 0, 0};
    for (int ch = 0; ch < NCH; ++ch) {
        const float4* src = (const float4*)(es_part + ((size_t)ch * 64 + m) * 2048 + t * 8);
        float4 a = src[0], b4 = src[1];
        v[0] += a.x; v[1] += a.y; v[2] += a.z; v[3] += a.w;
        v[4] += b4.x; v[5] += b4.y; v[6] += b4.z; v[7] += b4.w;
    }
    float4* dst = (float4*)(es + m * 2048 + t * 8);
    dst[0] = make_float4(v[0], v[1], v[2], v[3]);
    dst[1] = make_float4(v[4], v[5], v[6], v[7]);
    int b = t >> 4, c0 = (t & 15) * 8;
    float qd = 0.f, tp = 0.f;
#pragma unroll
    for (int j = 0; j < 8; ++j) {
        qd += v[j] * att[128 + c0 + j];
        tp += v[j];
    }
#pragma unroll
    for (int k = 1; k < 16; k <<= 1) {
        qd += __shfl_xor(qd, k, 64);
        tp += __shfl_xor(tp, k, 64);
    }
    if ((t & 15) == 0) q[m * 16 + b] = qd;
    tp += __shfl_xor(tp, 16, 64);
    tp += __shfl_xor(tp, 32, 64);
    __shared__ float ws4[4];
    if ((t & 63) == 0) ws4[t >> 6] = tp;
    __syncthreads();
    if (t == 0) T[m] = ws4[0] + ws4[1] + ws4[2] + ws4[3];
}

// ---------------- pairwise hyperedge loss (norms inline) ----------------
__global__ __launch_bounds__(256) void loss_kernel(const float* __restrict__ es,
                                                   float* __restrict__ loss_part) {
    int m = blockIdx.x, t = threadIdx.x;
    __shared__ float esm[2048];
    __shared__ float sml[16];
    for (int i = t; i < 2048; i += 256) esm[i] = es[m * 2048 + i];
    __syncthreads();
    if (t < 16) {
        float s = 0.f;
        const float* r = esm + t * 128;
        for (int c = 0; c < 128; ++c) s += r[c] * r[c];
        sml[t] = s;
    }
    __syncthreads();
    int n = t >> 2, bq = t & 3;
    float part = 0.f;
#pragma unroll
    for (int u = 0; u < 4; u++) {
        int b = bq * 4 + u;
        float inner = 0.f, sn = 0.f;
        const float* er = es + n * 2048 + b * 128;
        const float* em = esm + b * 128;
        for (int c = 0; c < 128; c += 4) {
            float4 a = *(const float4*)(em + c);
            float4 o = *(const float4*)(er + c);
            inner += a.x * o.x + a.y * o.y + a.z * o.z + a.w * o.w;
            sn += o.x * o.x + o.y * o.y + o.z * o.z + o.w * o.w;
        }
        float sm = sml[b];
        float cosv = inner / (sqrtf(sm) * sqrtf(sn));
        float d2 = sm + sn - 2.f * inner;
        float dist = sqrtf(fmaxf(d2, 0.f));
        part += cosv * dist + (1.f - cosv) * fmaxf(MARGIN - dist, 0.f);
    }
    part += __shfl_xor(part, 1, 64);
    part += __shfl_xor(part, 2, 64);
    float labs = fabsf(part * (1.f / 16.f));
    __shared__ float pl[64];
    if (bq == 0) pl[n] = labs;
    __syncthreads();
    if (t < 64) {
        float v = pl[t];
        for (int k = 1; k < 64; k <<= 1) v += __shfl_xor(v, k, 64);
        if (t == 0) loss_part[m] = v;
    }
}

// ---------------- alpha DENSE: counts-weighted softmax over 64 m; no atomics ----------
// alpha depends only on (n,m,b): Wa[b][m][n] = cnt(n,m)*alpha; Wb[b][n][m] = cnt*alpha/deg_m.
// Each (n,b) thread is the unique writer of its Wa/Wb entries -> plain stores.
__global__ __launch_bounds__(256) void alpha_wab(const float* __restrict__ AcntT,
                                                 const float* __restrict__ p,
                                                 const float* __restrict__ q,
                                                 const int* __restrict__ deg_m,
                                                 float* __restrict__ Wa,
                                                 float* __restrict__ Wb) {
    __shared__ float acl[16][68];   // 16 n-rows x 64 m (+4 pad)
    __shared__ float qs[64][16];    // q[m][b]
    int t = threadIdx.x;
    int n0 = blockIdx.x * 16;
    {   // stage AcntT rows and q
        int row = t >> 4, c4 = (t & 15) * 4;
        *(float4*)&acl[row][c4] = *(const float4*)(AcntT + (size_t)(n0 + row) * 64 + c4);
        int mq = t >> 2, bq4 = (t & 3) * 4;
        *(float4*)&qs[mq][bq4] = *(const float4*)(q + mq * 16 + bq4);
    }
    __syncthreads();
    int b = t & 15, tn = t >> 4;
    int n = n0 + tn;
    float pb = p[n * 16 + b];
    float mx = -1e30f;
    for (int m = 0; m < 64; ++m) {
        if (acl[tn][m] > 0.f) {
            float lg = pb + qs[m][b];
            lg = lg >= 0.f ? lg : NEG_SLOPE * lg;
            mx = fmaxf(mx, lg);
        }
    }
    float ssum = 0.f;
    for (int m = 0; m < 64; ++m) {
        float cnt = acl[tn][m];
        if (cnt > 0.f) {
            float lg = pb + qs[m][b];
            lg = lg >= 0.f ? lg : NEG_SLOPE * lg;
            ssum += cnt * __expf(lg - mx);
        }
    }
    if (ssum == 0.f) return;
    float inv = 1.f / ssum;
    for (int m = 0; m < 64; ++m) {
        float cnt = acl[tn][m];
        if (cnt > 0.f) {
            float lg = pb + qs[m][b];
            lg = lg >= 0.f ? lg : NEG_SLOPE * lg;
            float a = cnt * __expf(lg - mx) * inv;
            Wa[((size_t)b * 64 + m) * 4096 + n] = a;
            Wb[((size_t)b * 4096 + n) * 64 + m] = a / (float)deg_m[m];
        }
    }
}

// ---------------- ouT GEMM (K-split, NO atomics): partial per chunk -------------------
__global__ __launch_bounds__(256) void oute_gemm(const unsigned short* __restrict__ xwTh,
                                                 const unsigned short* __restrict__ xwTl,
                                                 const float* __restrict__ Wa,
                                                 float* __restrict__ ouT_part) {
    int t = threadIdx.x, w = t >> 6, l = t & 63;
    int lrow = l & 15, lk = l >> 4;
    int slot0 = blockIdx.x * 64;
    int b = slot0 >> 7;
    int kbase = blockIdx.y * (4096 / NCH);
    f32x4 acc[4];
#pragma unroll
    for (int tj = 0; tj < 4; ++tj) acc[tj] = (f32x4){0.f, 0.f, 0.f, 0.f};
    int srow = slot0 + w * 16 + lrow;
    const unsigned short* xh = xwTh + (size_t)srow * 4096;
    const unsigned short* xl = xwTl + (size_t)srow * 4096;
    const float* wab = Wa + (size_t)b * 64 * 4096;
#pragma unroll
    for (int ks = 0; ks < 4096 / NCH / 32; ++ks) {
        int n0 = kbase + ks * 32 + lk * 8;
        bfrag ah = *(const bfrag*)(xh + n0);
        bfrag al = *(const bfrag*)(xl + n0);
#pragma unroll
        for (int tj = 0; tj < 4; ++tj) {
            int mcol = tj * 16 + lrow;
            bfrag wh, wl_;
            split8(wab + (size_t)mcol * 4096 + n0, wh, wl_);
            acc[tj] = __builtin_amdgcn_mfma_f32_16x16x32_bf16(ah, wh, acc[tj], 0, 0, 0);
            acc[tj] = __builtin_amdgcn_mfma_f32_16x16x32_bf16(ah, wl_, acc[tj], 0, 0, 0);
            acc[tj] = __builtin_amdgcn_mfma_f32_16x16x32_bf16(al, wh, acc[tj], 0, 0, 0);
        }
    }
    float* dst = ouT_part + (size_t)blockIdx.y * 2048 * 64;
#pragma unroll
    for (int tj = 0; tj < 4; ++tj) {
        int mcol = tj * 16 + lrow;
#pragma unroll
        for (int reg = 0; reg < 4; ++reg) {
            int slot = slot0 + w * 16 + lk * 4 + reg;
            dst[slot * 64 + mcol] = acc[tj][reg];
        }
    }
}

// ---------------- ouT reduce ----------------
__global__ __launch_bounds__(256) void oute_reduce(const float* __restrict__ ouT_part,
                                                   float* __restrict__ ouT) {
    int idx = blockIdx.x * 256 + threadIdx.x;  // 32768 = 2048*64/4
    int slot = idx >> 4, m4 = (idx & 15) * 4;
    float4 s = make_float4(0.f, 0.f, 0.f, 0.f);
    for (int ch = 0; ch < NCH; ++ch) {
        float4 a = *(const float4*)(ouT_part + ((size_t)ch * 2048 + slot) * 64 + m4);
        s.x += a.x; s.y += a.y; s.z += a.z; s.w += a.w;
    }
    *(float4*)(ouT + (size_t)slot * 64 + m4) = s;
}

// ---------------- out GEMM: out[b][n][c] = D[n]*sum_m Wb[b][n][m]*ouT[b*128+c][m] -----
__global__ __launch_bounds__(256) void out_gemm(const float* __restrict__ Wb,
                                                const float* __restrict__ ouT,
                                                const int* __restrict__ deg_n,
                                                float* __restrict__ out) {
    int t = threadIdx.x, w = t >> 6, l = t & 63;
    int lrow = l & 15, lk = l >> 4;
    int nbase = blockIdx.x * 64 + w * 16;
    int b = blockIdx.y;
    f32x4 acc[8];
#pragma unroll
    for (int tj = 0; tj < 8; ++tj) acc[tj] = (f32x4){0.f, 0.f, 0.f, 0.f};
#pragma unroll
    for (int ks = 0; ks < 2; ++ks) {
        int m0 = ks * 32 + lk * 8;
        bfrag wh, wl;
        int nr = nbase + lrow;
        split8(Wb + ((size_t)b * 4096 + nr) * 64 + m0, wh, wl);
#pragma unroll
        for (int tj = 0; tj < 8; ++tj) {
            int slot = b * 128 + tj * 16 + lrow;
            bfrag oh, ol;
            split8(ouT + (size_t)slot * 64 + m0, oh, ol);
            acc[tj] = __builtin_amdgcn_mfma_f32_16x16x32_bf16(wh, oh, acc[tj], 0, 0, 0);
            acc[tj] = __builtin_amdgcn_mfma_f32_16x16x32_bf16(wh, ol, acc[tj], 0, 0, 0);
            acc[tj] = __builtin_amdgcn_mfma_f32_16x16x32_bf16(wl, oh, acc[tj], 0, 0, 0);
        }
    }
#pragma unroll
    for (int reg = 0; reg < 4; ++reg) {
        int n = nbase + lk * 4 + reg;
        float d = (float)deg_n[n];
#pragma unroll
        for (int tj = 0; tj < 8; ++tj) {
            out[(size_t)b * 524288 + (size_t)n * 128 + tj * 16 + lrow] = d * acc[tj][reg];
        }
    }
}

// ---------------- finalize scalar ----------------
__global__ __launch_bounds__(256) void finalize_kernel(const int* __restrict__ deg_n,
                                                       const float* __restrict__ S1,
                                                       const int* __restrict__ deg_m,
                                                       const float* __restrict__ T,
                                                       const float* __restrict__ loss_part,
                                                       float* __restrict__ out_scalar) {
    int t = threadIdx.x;
    double a = 0.0;
    for (int n = t; n < 4096; n += 256) a += (double)deg_n[n] * (double)S1[n];
    double bsum = 0.0, lsum = 0.0;
    if (t < 64) {
        bsum = (double)deg_m[t] * (double)T[t];
        lsum = (double)loss_part[t];
    }
    __shared__ double sa[256], sb[256], sl[256];
    sa[t] = a; sb[t] = bsum; sl[t] = lsum;
    __syncthreads();
    for (int s = 128; s > 0; s >>= 1) {
        if (t < s) { sa[t] += sa[t + s]; sb[t] += sb[t + s]; sl[t] += sl[t + s]; }
        __syncthreads();
    }
    if (t == 0) {
        double mean = (sa[0] - sb[0]) / 25165824.0;  // E*B*C
        out_scalar[0] = (float)(fabs(mean) + sl[0] / 4225.0);
    }
}

extern "C" void kernel_launch(void* const* d_in, const int* in_sizes, int n_in,
                              void* d_out, int out_size, void* d_ws, size_t ws_size,
                              hipStream_t stream) {
    const float* x = (const float*)d_in[0];
    const int* nodes = (const int*)d_in[1];
    const int* edges = (const int*)d_in[2];
    const float* w = (const float*)d_in[3];
    const float* att = (const float*)d_in[4];
    float* out = (float*)d_out;

    char* ws = (char*)d_ws;
    size_t o = 0;
    unsigned short* xwTh = (unsigned short*)(ws + o); o += (size_t)2048 * 4096 * 2;  // 16 MB
    unsigned short* xwTl = (unsigned short*)(ws + o); o += (size_t)2048 * 4096 * 2;  // 16 MB
    float* es_part = (float*)(ws + o);  o += (size_t)NCH * Mm * 2048 * 4;            // 16 MB
    float* ouT_part = (float*)(ws + o); o += (size_t)NCH * 2048 * Mm * 4;            // 16 MB
    // ---- zero region (one memset): Acnt, AcntT, Wa, Wb, deg_n, deg_m, S1 ----
    size_t zbase = o;
    float* Acnt = (float*)(ws + o);  o += (size_t)Mm * Nn * 4;            // 1 MB
    float* AcntT = (float*)(ws + o); o += (size_t)Nn * Mm * 4;            // 1 MB
    float* Wa = (float*)(ws + o);    o += (size_t)Bc * Mm * Nn * 4;       // 16 MB
    float* Wb = (float*)(ws + o);    o += (size_t)Bc * Nn * Mm * 4;       // 16 MB
    int* deg_n = (int*)(ws + o);     o += (size_t)Nn * 4;
    int* deg_m = (int*)(ws + o);     o += (size_t)Mm * 4;
    float* S1 = (float*)(ws + o);    o += (size_t)Nn * 4;
    size_t zlen = o - zbase;
    // ---- end zero region ----
    float* es = (float*)(ws + o);        o += (size_t)Mm * 2048 * 4;      // 512 KB
    float* ouT = (float*)(ws + o);       o += (size_t)2048 * Mm * 4;      // 512 KB
    float* p = (float*)(ws + o);         o += (size_t)Nn * Bc * 4;        // 256 KB
    float* q = (float*)(ws + o);         o += (size_t)Mm * Bc * 4;
    float* T = (float*)(ws + o);         o += (size_t)Mm * 4;
    float* loss_part = (float*)(ws + o); o += (size_t)Mm * 4;
    unsigned short* wsplit = (unsigned short*)(ws + o); o += 65536;       // 64 KB

    hipMemsetAsync(ws + zbase, 0, zlen, stream);

    prep_kernel<<<112, 256, 0, stream>>>(w, nodes, edges, wsplit, deg_n, deg_m, Acnt, AcntT);
    gemm_xw<<<512, 256, 0, stream>>>(x, wsplit, att, xwTh, xwTl, p, S1);
    es_gemm<<<dim3(32, NCH), 256, 0, stream>>>(Acnt, xwTh, xwTl, es_part);
    es_reduce<<<Mm, 256, 0, stream>>>(es_part, att, es, q, T);
    loss_kernel<<<Mm, 256, 0, stream>>>(es, loss_part);
    alpha_wab<<<256, 256, 0, stream>>>(AcntT, p, q, deg_m, Wa, Wb);
    oute_gemm<<<dim3(32, NCH), 256, 0, stream>>>(xwTh, xwTl, Wa, ouT_part);
    oute_reduce<<<128, 256, 0, stream>>>(ouT_part, ouT);
    out_gemm<<<dim3(64, 16), 256, 0, stream>>>(Wb, ouT, deg_n, out);
    finalize_kernel<<<1, 256, 0, stream>>>(deg_n, S1, deg_m, T, loss_part, out + (size_t)Bc * Nn * Cc);
}

// Round 11
// 250.806 us; speedup vs baseline: 1.4790x; 1.0043x over previous
//
#include <hip/hip_runtime.h>
#include <hip/hip_bf16.h>

#define Bc 16
#define Nn 4096
#define Cc 128
#define Ee 12288
#define Mm 64
#define NEG_SLOPE 0.2f
#define MARGIN 4.2f
#define NCH 32  // K-split chunks for es/oute GEMMs -> 1024 blocks, partial-buffer reduce

typedef __attribute__((ext_vector_type(8))) short bfrag;   // 8 bf16 = 4 VGPR
typedef __attribute__((ext_vector_type(4))) float f32x4;   // MFMA accumulator

// split f32 -> bf16 hi (trunc) + bf16 lo (rne of residual)
__device__ inline void split1(float f, unsigned short& h, unsigned short& lo) {
    unsigned u = __float_as_uint(f);
    unsigned hb = u & 0xFFFF0000u;
    float r = f - __uint_as_float(hb);
    unsigned ru = __float_as_uint(r);
    ru += 0x7FFFu + ((ru >> 16) & 1u);
    h = (unsigned short)(u >> 16);
    lo = (unsigned short)(ru >> 16);
}

// ---------------- prep: wsplit (blocks 0-63) + hist/Acnt/AcntT (blocks 64-111) --------
// wsplit layout: per k-half h (k<64 | k>=64): [h*32KB, h*32KB+16KB) hi, +16KB lo.
// Within a half: byte = c*128 + ((2*(k&63)) ^ ((c&7)<<4))   (XOR swizzle, 128B rows).
__global__ __launch_bounds__(256) void prep_kernel(const float* __restrict__ w,
                                                   const int* __restrict__ nodes,
                                                   const int* __restrict__ edges,
                                                   unsigned short* __restrict__ wsplit,
                                                   int* __restrict__ deg_n,
                                                   int* __restrict__ deg_m,
                                                   float* __restrict__ Acnt,
                                                   float* __restrict__ AcntT) {
    int blk = blockIdx.x, t = threadIdx.x;
    if (blk < 64) {
        int idx = blk * 256 + t;  // 16384 = 128*128
        int k = idx >> 7, c = idx & 127;
        float v = w[k * 128 + c];
        unsigned short h, lo;
        split1(v, h, lo);
        int half = k >> 6, kk = k & 63;
        int byteoff = half * 32768 + c * 128 + ((2 * kk) ^ ((c & 7) << 4));
        *(unsigned short*)((char*)wsplit + byteoff) = h;
        *(unsigned short*)((char*)wsplit + byteoff + 16384) = lo;
    } else {
        int e = (blk - 64) * 256 + t;  // 12288 = 48*256
        int n = nodes[e], m = edges[e];
        atomicAdd(&deg_n[n], 1);
        atomicAdd(&deg_m[m], 1);
        atomicAdd(&Acnt[m * 4096 + n], 1.0f);
        atomicAdd(&AcntT[n * 64 + m], 1.0f);
    }
}

// ---------------- GEMM via bf16 split MFMA: xwT = (x @ w)^T as bf16 hi/lo -------------
// 32KB LDS (one k-half of w, hi+lo) restaged twice -> 4 blocks/CU (was 2 with 64KB).
__global__ __launch_bounds__(256) void gemm_xw(const float* __restrict__ x,
                                               const unsigned short* __restrict__ wsplit,
                                               const float* __restrict__ att,
                                               unsigned short* __restrict__ xwTh,
                                               unsigned short* __restrict__ xwTl,
                                               float* __restrict__ p,
                                               float* __restrict__ S1) {
    __shared__ unsigned short wlds[16384];  // 32KB: one half (hi 16KB | lo 16KB)
    int t = threadIdx.x;
    int w = t >> 6, l = t & 63;
    int lrow = l & 15, lk = l >> 4;
    int rowbase = blockIdx.x * 128 + w * 32;

    f32x4 acc[2][8];
#pragma unroll
    for (int ti = 0; ti < 2; ++ti)
#pragma unroll
        for (int tj = 0; tj < 8; ++tj) acc[ti][tj] = (f32x4){0.f, 0.f, 0.f, 0.f};

    for (int half = 0; half < 2; ++half) {
        {   // stage 32KB (hi+lo of this k-half)
            const float4* g4 = (const float4*)(wsplit + (size_t)half * 16384);
            float4* l4 = (float4*)wlds;
#pragma unroll
            for (int i = 0; i < 8; ++i) l4[i * 256 + t] = g4[i * 256 + t];
        }
        __syncthreads();
#pragma unroll
        for (int ks2 = 0; ks2 < 2; ++ks2) {
            bfrag bh[8], bl[8];
            int kbyte = (64 * ks2 + 16 * lk) ^ ((l & 7) << 4);
#pragma unroll
            for (int tj = 0; tj < 8; ++tj) {
                const char* base = (const char*)wlds + (tj * 16 + lrow) * 128 + kbyte;
                bh[tj] = *(const bfrag*)base;
                bl[tj] = *(const bfrag*)(base + 16384);
            }
#pragma unroll
            for (int ti = 0; ti < 2; ++ti) {
                int row = rowbase + ti * 16 + lrow;
                const float4* xp = (const float4*)(x + (size_t)row * 128 + half * 64 + ks2 * 32 + lk * 8);
                float4 v0 = xp[0], v1 = xp[1];
                float fa[8] = {v0.x, v0.y, v0.z, v0.w, v1.x, v1.y, v1.z, v1.w};
                bfrag ah, al;
#pragma unroll
                for (int j = 0; j < 8; ++j) {
                    unsigned short hh, ll;
                    split1(fa[j], hh, ll);
                    ah[j] = (short)hh; al[j] = (short)ll;
                }
#pragma unroll
                for (int tj = 0; tj < 8; ++tj) {
                    acc[ti][tj] = __builtin_amdgcn_mfma_f32_16x16x32_bf16(ah, bh[tj], acc[ti][tj], 0, 0, 0);
                    acc[ti][tj] = __builtin_amdgcn_mfma_f32_16x16x32_bf16(ah, bl[tj], acc[ti][tj], 0, 0, 0);
                    acc[ti][tj] = __builtin_amdgcn_mfma_f32_16x16x32_bf16(al, bh[tj], acc[ti][tj], 0, 0, 0);
                }
            }
        }
        __syncthreads();
    }

    // epilogue A: xwT packed bf16 hi/lo writes
#pragma unroll
    for (int ti = 0; ti < 2; ++ti) {
#pragma unroll
        for (int tj = 0; tj < 8; ++tj) {
            int rr0 = rowbase + ti * 16 + lk * 4;
            int b = rr0 >> 12, n0 = rr0 & 4095;
            int slot = b * 128 + tj * 16 + lrow;
            ushort4 hv, lv;
            split1(acc[ti][tj][0], hv.x, lv.x);
            split1(acc[ti][tj][1], hv.y, lv.y);
            split1(acc[ti][tj][2], hv.z, lv.z);
            split1(acc[ti][tj][3], hv.w, lv.w);
            *(ushort4*)(xwTh + (size_t)slot * 4096 + n0) = hv;
            *(ushort4*)(xwTl + (size_t)slot * 4096 + n0) = lv;
        }
    }
    // epilogue B: p / S1 (full f32 precision)
    float aw_[8];
#pragma unroll
    for (int tj = 0; tj < 8; ++tj) aw_[tj] = att[tj * 16 + lrow];
#pragma unroll
    for (int ti = 0; ti < 2; ++ti) {
#pragma unroll
        for (int v = 0; v < 4; ++v) {
            int rr = rowbase + ti * 16 + lk * 4 + v;
            int b = rr >> 12, n = rr & 4095;
            float pd = 0.f, ss = 0.f;
#pragma unroll
            for (int tj = 0; tj < 8; ++tj) {
                float val = acc[ti][tj][v];
                pd += val * aw_[tj];
                ss += val;
            }
#pragma unroll
            for (int m = 1; m < 16; m <<= 1) {
                pd += __shfl_xor(pd, m, 64);
                ss += __shfl_xor(ss, m, 64);
            }
            if (lrow == 0) {
                p[n * 16 + b] = pd;
                atomicAdd(&S1[n], ss);   // 16K small atomics total, negligible
            }
        }
    }
}

// ---------------- es GEMM (K-split, NO atomics): partial per chunk --------------------
__global__ __launch_bounds__(256) void es_gemm(const float* __restrict__ Acnt,
                                               const unsigned short* __restrict__ xwTh,
                                               const unsigned short* __restrict__ xwTl,
                                               float* __restrict__ es_part) {
    int t = threadIdx.x, w = t >> 6, l = t & 63;
    int lrow = l & 15, lk = l >> 4;
    int slot0 = blockIdx.x * 64;
    int kbase = blockIdx.y * (4096 / NCH);
    f32x4 acc[4];
#pragma unroll
    for (int tj = 0; tj < 4; ++tj) acc[tj] = (f32x4){0.f, 0.f, 0.f, 0.f};
    const float* arow = Acnt + (size_t)(w * 16 + lrow) * 4096;
#pragma unroll
    for (int ks = 0; ks < 4096 / NCH / 32; ++ks) {
        int n0 = kbase + ks * 32 + lk * 8;
        const float* ap = arow + n0;
        bfrag af;
#pragma unroll
        for (int j = 0; j < 8; ++j) af[j] = (short)(__float_as_uint(ap[j]) >> 16);  // counts exact
#pragma unroll
        for (int tj = 0; tj < 4; ++tj) {
            size_t off = (size_t)(slot0 + tj * 16 + lrow) * 4096 + n0;
            bfrag bh = *(const bfrag*)(xwTh + off);
            bfrag bl = *(const bfrag*)(xwTl + off);
            acc[tj] = __builtin_amdgcn_mfma_f32_16x16x32_bf16(af, bh, acc[tj], 0, 0, 0);
            acc[tj] = __builtin_amdgcn_mfma_f32_16x16x32_bf16(af, bl, acc[tj], 0, 0, 0);
        }
    }
    float* dst = es_part + (size_t)blockIdx.y * 64 * 2048;
#pragma unroll
    for (int tj = 0; tj < 4; ++tj) {
        int slot = slot0 + tj * 16 + lrow;
#pragma unroll
        for (int reg = 0; reg < 4; ++reg) {
            int mm = w * 16 + lk * 4 + reg;
            dst[mm * 2048 + slot] = acc[tj][reg];
        }
    }
}

// ---------------- es reduce: es = sum_ch es_part; fused q[m][b], T[m] -----------------
__global__ __launch_bounds__(256) void es_reduce(const float* __restrict__ es_part,
                                                 const float* __restrict__ att,
                                                 float* __restrict__ es,
                                                 float* __restrict__ q,
                                                 float* __restrict__ T) {
    int m = blockIdx.x, t = threadIdx.x;
    float v[8] = {0, 0, 0, 0, 0, 0, 0, 0};
    for (int ch = 0; ch < NCH; ++ch) {
        const float4* src = (const float4*)(es_part + ((size_t)ch * 64 + m) * 2048 + t * 8);
        float4 a = src[0], b4 = src[1];
        v[0] += a.x; v[1] += a.y; v[2] += a.z; v[3] += a.w;
        v[4] += b4.x; v[5] += b4.y; v[6] += b4.z; v[7] += b4.w;
    }
    float4* dst = (float4*)(es + m * 2048 + t * 8);
    dst[0] = make_float4(v[0], v[1], v[2], v[3]);
    dst[1] = make_float4(v[4], v[5], v[6], v[7]);
    int b = t >> 4, c0 = (t & 15) * 8;
    float qd = 0.f, tp = 0.f;
#pragma unroll
    for (int j = 0; j < 8; ++j) {
        qd += v[j] * att[128 + c0 + j];
        tp += v[j];
    }
#pragma unroll
    for (int k = 1; k < 16; k <<= 1) {
        qd += __shfl_xor(qd, k, 64);
        tp += __shfl_xor(tp, k, 64);
    }
    if ((t & 15) == 0) q[m * 16 + b] = qd;
    tp += __shfl_xor(tp, 16, 64);
    tp += __shfl_xor(tp, 32, 64);
    __shared__ float ws4[4];
    if ((t & 63) == 0) ws4[t >> 6] = tp;
    __syncthreads();
    if (t == 0) T[m] = ws4[0] + ws4[1] + ws4[2] + ws4[3];
}

// ---------------- pairwise hyperedge loss (norms inline) ----------------
__global__ __launch_bounds__(256) void loss_kernel(const float* __restrict__ es,
                                                   float* __restrict__ loss_part) {
    int m = blockIdx.x, t = threadIdx.x;
    __shared__ float esm[2048];
    __shared__ float sml[16];
    for (int i = t; i < 2048; i += 256) esm[i] = es[m * 2048 + i];
    __syncthreads();
    if (t < 16) {
        float s = 0.f;
        const float* r = esm + t * 128;
        for (int c = 0; c < 128; ++c) s += r[c] * r[c];
        sml[t] = s;
    }
    __syncthreads();
    int n = t >> 2, bq = t & 3;
    float part = 0.f;
#pragma unroll
    for (int u = 0; u < 4; u++) {
        int b = bq * 4 + u;
        float inner = 0.f, sn = 0.f;
        const float* er = es + n * 2048 + b * 128;
        const float* em = esm + b * 128;
        for (int c = 0; c < 128; c += 4) {
            float4 a = *(const float4*)(em + c);
            float4 o = *(const float4*)(er + c);
            inner += a.x * o.x + a.y * o.y + a.z * o.z + a.w * o.w;
            sn += o.x * o.x + o.y * o.y + o.z * o.z + o.w * o.w;
        }
        float sm = sml[b];
        float cosv = inner / (sqrtf(sm) * sqrtf(sn));
        float d2 = sm + sn - 2.f * inner;
        float dist = sqrtf(fmaxf(d2, 0.f));
        part += cosv * dist + (1.f - cosv) * fmaxf(MARGIN - dist, 0.f);
    }
    part += __shfl_xor(part, 1, 64);
    part += __shfl_xor(part, 2, 64);
    float labs = fabsf(part * (1.f / 16.f));
    __shared__ float pl[64];
    if (bq == 0) pl[n] = labs;
    __syncthreads();
    if (t < 64) {
        float v = pl[t];
        for (int k = 1; k < 64; k <<= 1) v += __shfl_xor(v, k, 64);
        if (t == 0) loss_part[m] = v;
    }
}

// ---------------- alpha DENSE softmax; writes Wa/Wb pre-split to bf16 hi/lo -----------
__global__ __launch_bounds__(256) void alpha_wab(const float* __restrict__ AcntT,
                                                 const float* __restrict__ p,
                                                 const float* __restrict__ q,
                                                 const int* __restrict__ deg_m,
                                                 unsigned short* __restrict__ Wah,
                                                 unsigned short* __restrict__ Wal,
                                                 unsigned short* __restrict__ Wbh,
                                                 unsigned short* __restrict__ Wbl) {
    __shared__ float acl[16][68];   // 16 n-rows x 64 m (+4 pad)
    __shared__ float qs[64][16];    // q[m][b]
    int t = threadIdx.x;
    int n0 = blockIdx.x * 16;
    {
        int row = t >> 4, c4 = (t & 15) * 4;
        *(float4*)&acl[row][c4] = *(const float4*)(AcntT + (size_t)(n0 + row) * 64 + c4);
        int mq = t >> 2, bq4 = (t & 3) * 4;
        *(float4*)&qs[mq][bq4] = *(const float4*)(q + mq * 16 + bq4);
    }
    __syncthreads();
    int b = t & 15, tn = t >> 4;
    int n = n0 + tn;
    float pb = p[n * 16 + b];
    float mx = -1e30f;
    for (int m = 0; m < 64; ++m) {
        if (acl[tn][m] > 0.f) {
            float lg = pb + qs[m][b];
            lg = lg >= 0.f ? lg : NEG_SLOPE * lg;
            mx = fmaxf(mx, lg);
        }
    }
    float ssum = 0.f;
    for (int m = 0; m < 64; ++m) {
        float cnt = acl[tn][m];
        if (cnt > 0.f) {
            float lg = pb + qs[m][b];
            lg = lg >= 0.f ? lg : NEG_SLOPE * lg;
            ssum += cnt * __expf(lg - mx);
        }
    }
    if (ssum == 0.f) return;
    float inv = 1.f / ssum;
    for (int m = 0; m < 64; ++m) {
        float cnt = acl[tn][m];
        if (cnt > 0.f) {
            float lg = pb + qs[m][b];
            lg = lg >= 0.f ? lg : NEG_SLOPE * lg;
            float a = cnt * __expf(lg - mx) * inv;
            unsigned short h, lo;
            split1(a, h, lo);
            size_t ia = ((size_t)b * 64 + m) * 4096 + n;
            Wah[ia] = h; Wal[ia] = lo;
            float wbv = a / (float)deg_m[m];
            split1(wbv, h, lo);
            size_t ib = ((size_t)b * 4096 + n) * 64 + m;
            Wbh[ib] = h; Wbl[ib] = lo;
        }
    }
}

// ---------------- ouT GEMM (K-split, NO atomics): partial per chunk -------------------
__global__ __launch_bounds__(256) void oute_gemm(const unsigned short* __restrict__ xwTh,
                                                 const unsigned short* __restrict__ xwTl,
                                                 const unsigned short* __restrict__ Wah,
                                                 const unsigned short* __restrict__ Wal,
                                                 float* __restrict__ ouT_part) {
    int t = threadIdx.x, w = t >> 6, l = t & 63;
    int lrow = l & 15, lk = l >> 4;
    int slot0 = blockIdx.x * 64;
    int b = slot0 >> 7;
    int kbase = blockIdx.y * (4096 / NCH);
    f32x4 acc[4];
#pragma unroll
    for (int tj = 0; tj < 4; ++tj) acc[tj] = (f32x4){0.f, 0.f, 0.f, 0.f};
    int srow = slot0 + w * 16 + lrow;
    const unsigned short* xh = xwTh + (size_t)srow * 4096;
    const unsigned short* xl = xwTl + (size_t)srow * 4096;
    const unsigned short* wah = Wah + (size_t)b * 64 * 4096;
    const unsigned short* wal = Wal + (size_t)b * 64 * 4096;
#pragma unroll
    for (int ks = 0; ks < 4096 / NCH / 32; ++ks) {
        int n0 = kbase + ks * 32 + lk * 8;
        bfrag ah = *(const bfrag*)(xh + n0);
        bfrag al = *(const bfrag*)(xl + n0);
#pragma unroll
        for (int tj = 0; tj < 4; ++tj) {
            int mcol = tj * 16 + lrow;
            bfrag wh = *(const bfrag*)(wah + (size_t)mcol * 4096 + n0);
            bfrag wl_ = *(const bfrag*)(wal + (size_t)mcol * 4096 + n0);
            acc[tj] = __builtin_amdgcn_mfma_f32_16x16x32_bf16(ah, wh, acc[tj], 0, 0, 0);
            acc[tj] = __builtin_amdgcn_mfma_f32_16x16x32_bf16(ah, wl_, acc[tj], 0, 0, 0);
            acc[tj] = __builtin_amdgcn_mfma_f32_16x16x32_bf16(al, wh, acc[tj], 0, 0, 0);
        }
    }
    float* dst = ouT_part + (size_t)blockIdx.y * 2048 * 64;
#pragma unroll
    for (int tj = 0; tj < 4; ++tj) {
        int mcol = tj * 16 + lrow;
#pragma unroll
        for (int reg = 0; reg < 4; ++reg) {
            int slot = slot0 + w * 16 + lk * 4 + reg;
            dst[slot * 64 + mcol] = acc[tj][reg];
        }
    }
}

// ---------------- ouT reduce -> bf16 hi/lo ----------------
__global__ __launch_bounds__(256) void oute_reduce(const float* __restrict__ ouT_part,
                                                   unsigned short* __restrict__ ouTh,
                                                   unsigned short* __restrict__ ouTl) {
    int idx = blockIdx.x * 256 + threadIdx.x;  // 32768 = 2048*64/4
    int slot = idx >> 4, m4 = (idx & 15) * 4;
    float4 s = make_float4(0.f, 0.f, 0.f, 0.f);
    for (int ch = 0; ch < NCH; ++ch) {
        float4 a = *(const float4*)(ouT_part + ((size_t)ch * 2048 + slot) * 64 + m4);
        s.x += a.x; s.y += a.y; s.z += a.z; s.w += a.w;
    }
    ushort4 hv, lv;
    split1(s.x, hv.x, lv.x);
    split1(s.y, hv.y, lv.y);
    split1(s.z, hv.z, lv.z);
    split1(s.w, hv.w, lv.w);
    *(ushort4*)(ouTh + (size_t)slot * 64 + m4) = hv;
    *(ushort4*)(ouTl + (size_t)slot * 64 + m4) = lv;
}

// ---------------- out GEMM: out[b][n][c] = D[n]*sum_m Wb[b][n][m]*ouT[b*128+c][m] -----
__global__ __launch_bounds__(256) void out_gemm(const unsigned short* __restrict__ Wbh,
                                                const unsigned short* __restrict__ Wbl,
                                                const unsigned short* __restrict__ ouTh,
                                                const unsigned short* __restrict__ ouTl,
                                                const int* __restrict__ deg_n,
                                                float* __restrict__ out) {
    int t = threadIdx.x, w = t >> 6, l = t & 63;
    int lrow = l & 15, lk = l >> 4;
    int nbase = blockIdx.x * 64 + w * 16;
    int b = blockIdx.y;
    f32x4 acc[8];
#pragma unroll
    for (int tj = 0; tj < 8; ++tj) acc[tj] = (f32x4){0.f, 0.f, 0.f, 0.f};
#pragma unroll
    for (int ks = 0; ks < 2; ++ks) {
        int m0 = ks * 32 + lk * 8;
        int nr = nbase + lrow;
        bfrag wh = *(const bfrag*)(Wbh + ((size_t)b * 4096 + nr) * 64 + m0);
        bfrag wl = *(const bfrag*)(Wbl + ((size_t)b * 4096 + nr) * 64 + m0);
#pragma unroll
        for (int tj = 0; tj < 8; ++tj) {
            int slot = b * 128 + tj * 16 + lrow;
            bfrag oh = *(const bfrag*)(ouTh + (size_t)slot * 64 + m0);
            bfrag ol = *(const bfrag*)(ouTl + (size_t)slot * 64 + m0);
            acc[tj] = __builtin_amdgcn_mfma_f32_16x16x32_bf16(wh, oh, acc[tj], 0, 0, 0);
            acc[tj] = __builtin_amdgcn_mfma_f32_16x16x32_bf16(wh, ol, acc[tj], 0, 0, 0);
            acc[tj] = __builtin_amdgcn_mfma_f32_16x16x32_bf16(wl, oh, acc[tj], 0, 0, 0);
        }
    }
#pragma unroll
    for (int reg = 0; reg < 4; ++reg) {
        int n = nbase + lk * 4 + reg;
        float d = (float)deg_n[n];
#pragma unroll
        for (int tj = 0; tj < 8; ++tj) {
            out[(size_t)b * 524288 + (size_t)n * 128 + tj * 16 + lrow] = d * acc[tj][reg];
        }
    }
}

// ---------------- finalize scalar ----------------
__global__ __launch_bounds__(256) void finalize_kernel(const int* __restrict__ deg_n,
                                                       const float* __restrict__ S1,
                                                       const int* __restrict__ deg_m,
                                                       const float* __restrict__ T,
                                                       const float* __restrict__ loss_part,
                                                       float* __restrict__ out_scalar) {
    int t = threadIdx.x;
    double a = 0.0;
    for (int n = t; n < 4096; n += 256) a += (double)deg_n[n] * (double)S1[n];
    double bsum = 0.0, lsum = 0.0;
    if (t < 64) {
        bsum = (double)deg_m[t] * (double)T[t];
        lsum = (double)loss_part[t];
    }
    __shared__ double sa[256], sb[256], sl[256];
    sa[t] = a; sb[t] = bsum; sl[t] = lsum;
    __syncthreads();
    for (int s = 128; s > 0; s >>= 1) {
        if (t < s) { sa[t] += sa[t + s]; sb[t] += sb[t + s]; sl[t] += sl[t + s]; }
        __syncthreads();
    }
    if (t == 0) {
        double mean = (sa[0] - sb[0]) / 25165824.0;  // E*B*C
        out_scalar[0] = (float)(fabs(mean) + sl[0] / 4225.0);
    }
}

extern "C" void kernel_launch(void* const* d_in, const int* in_sizes, int n_in,
                              void* d_out, int out_size, void* d_ws, size_t ws_size,
                              hipStream_t stream) {
    const float* x = (const float*)d_in[0];
    const int* nodes = (const int*)d_in[1];
    const int* edges = (const int*)d_in[2];
    const float* w = (const float*)d_in[3];
    const float* att = (const float*)d_in[4];
    float* out = (float*)d_out;

    char* ws = (char*)d_ws;
    size_t o = 0;
    unsigned short* xwTh = (unsigned short*)(ws + o); o += (size_t)2048 * 4096 * 2;  // 16 MB
    unsigned short* xwTl = (unsigned short*)(ws + o); o += (size_t)2048 * 4096 * 2;  // 16 MB
    float* es_part = (float*)(ws + o);  o += (size_t)NCH * Mm * 2048 * 4;            // 16 MB
    float* ouT_part = (float*)(ws + o); o += (size_t)NCH * 2048 * Mm * 4;            // 16 MB
    // ---- zero region (one memset): Acnt, AcntT, Wah/Wal/Wbh/Wbl, deg_n, deg_m, S1 ----
    size_t zbase = o;
    float* Acnt = (float*)(ws + o);  o += (size_t)Mm * Nn * 4;                 // 1 MB
    float* AcntT = (float*)(ws + o); o += (size_t)Nn * Mm * 4;                 // 1 MB
    unsigned short* Wah = (unsigned short*)(ws + o); o += (size_t)Bc * Mm * Nn * 2;  // 8 MB
    unsigned short* Wal = (unsigned short*)(ws + o); o += (size_t)Bc * Mm * Nn * 2;  // 8 MB
    unsigned short* Wbh = (unsigned short*)(ws + o); o += (size_t)Bc * Nn * Mm * 2;  // 8 MB
    unsigned short* Wbl = (unsigned short*)(ws + o); o += (size_t)Bc * Nn * Mm * 2;  // 8 MB
    int* deg_n = (int*)(ws + o);     o += (size_t)Nn * 4;
    int* deg_m = (int*)(ws + o);     o += (size_t)Mm * 4;
    float* S1 = (float*)(ws + o);    o += (size_t)Nn * 4;
    size_t zlen = o - zbase;
    // ---- end zero region ----
    float* es = (float*)(ws + o);        o += (size_t)Mm * 2048 * 4;           // 512 KB
    unsigned short* ouTh = (unsigned short*)(ws + o); o += (size_t)2048 * Mm * 2;  // 256 KB
    unsigned short* ouTl = (unsigned short*)(ws + o); o += (size_t)2048 * Mm * 2;  // 256 KB
    float* p = (float*)(ws + o);         o += (size_t)Nn * Bc * 4;             // 256 KB
    float* q = (float*)(ws + o);         o += (size_t)Mm * Bc * 4;
    float* T = (float*)(ws + o);         o += (size_t)Mm * 4;
    float* loss_part = (float*)(ws + o); o += (size_t)Mm * 4;
    unsigned short* wsplit = (unsigned short*)(ws + o); o += 65536;            // 64 KB

    hipMemsetAsync(ws + zbase, 0, zlen, stream);

    prep_kernel<<<112, 256, 0, stream>>>(w, nodes, edges, wsplit, deg_n, deg_m, Acnt, AcntT);
    gemm_xw<<<512, 256, 0, stream>>>(x, wsplit, att, xwTh, xwTl, p, S1);
    es_gemm<<<dim3(32, NCH), 256, 0, stream>>>(Acnt, xwTh, xwTl, es_part);
    es_reduce<<<Mm, 256, 0, stream>>>(es_part, att, es, q, T);
    loss_kernel<<<Mm, 256, 0, stream>>>(es, loss_part);
    alpha_wab<<<256, 256, 0, stream>>>(AcntT, p, q, deg_m, Wah, Wal, Wbh, Wbl);
    oute_gemm<<<dim3(32, NCH), 256, 0, stream>>>(xwTh, xwTl, Wah, Wal, ouT_part);
    oute_reduce<<<128, 256, 0, stream>>>(ouT_part, ouTh, ouTl);
    out_gemm<<<dim3(64, 16), 256, 0, stream>>>(Wbh, Wbl, ouTh, ouTl, deg_n, out);
    finalize_kernel<<<1, 256, 0, stream>>>(deg_n, S1, deg_m, T, loss_part, out + (size_t)Bc * Nn * Cc);
}